// Round 3
// baseline (58.878 us; speedup 1.0000x reference)
//
#include <hip/hip_runtime.h>
#include <hip/hip_fp16.h>

#define INPUT_SIZE 128
#define NUM_REL 16

typedef int   i32x4 __attribute__((ext_vector_type(4)));
typedef float f32x4 __attribute__((ext_vector_type(4)));

// ---------------------------------------------------------------------------
// Kernel 1: per-node logit table, fp16 output.
//   L[n][r]    = x[n] . att_weight[0:128, r]      (r = 0..15, src half)
//   L[n][16+r] = x[n] . att_weight[128:256, r]    (dst half)
// Block: 256 threads = 128 nodes. Thread tile: 4 nodes x 4 relations.
// x is NT-loaded (stream, zero reuse beyond in-wave broadcast) so the L-table
// writes stay resident in L2 for kernel 2's gathers.
// ---------------------------------------------------------------------------
__global__ __launch_bounds__(256) void node_logits_kernel(
    const float* __restrict__ x,
    const float* __restrict__ w,     // (256,16) row-major
    __half* __restrict__ L,          // (num_nodes, 32) fp16
    int num_nodes)
{
    __shared__ float swc[128 * 32];  // swc[k*32 + r], 16 KB

    const int tid = threadIdx.x;

    // Stage + repack weights: swc[k][r] = r<16 ? w[k][r] : w[128+k][r-16]
    #pragma unroll
    for (int i = 0; i < 16; ++i) {
        const int idx = i * 256 + tid;        // 0..4095
        const int k = idx >> 5, r = idx & 31;
        swc[idx] = (r < 16) ? w[k * NUM_REL + r]
                            : w[(INPUT_SIZE + k) * NUM_REL + (r - 16)];
    }
    __syncthreads();

    const int ng = tid >> 3;                  // node group 0..31
    const int rg = tid & 7;                   // rel group  0..7
    const int node0 = blockIdx.x * 128 + ng * 4;
    const int r0 = rg * 4;

    const f32x4* xr[4];
    bool valid[4];
    #pragma unroll
    for (int n = 0; n < 4; ++n) {
        const int nn = node0 + n;
        valid[n] = (nn < num_nodes);
        const int cn = valid[n] ? nn : 0;     // clamp: safe read, store predicated
        xr[n] = (const f32x4*)(x + (size_t)cn * INPUT_SIZE);
    }

    float acc[4][4] = {};

    #pragma unroll 4
    for (int ks = 0; ks < 32; ++ks) {         // 4 k's per step
        f32x4 xv[4], wv[4];
        #pragma unroll
        for (int n = 0; n < 4; ++n)
            xv[n] = __builtin_nontemporal_load(&xr[n][ks]);
        #pragma unroll
        for (int kk = 0; kk < 4; ++kk)
            wv[kk] = *(const f32x4*)&swc[(ks * 4 + kk) * 32 + r0];

        #pragma unroll
        for (int n = 0; n < 4; ++n) {
            #pragma unroll
            for (int c = 0; c < 4; ++c) {     // xv component c pairs with wv[c]
                acc[n][0] += xv[n][c] * wv[c][0];
                acc[n][1] += xv[n][c] * wv[c][1];
                acc[n][2] += xv[n][c] * wv[c][2];
                acc[n][3] += xv[n][c] * wv[c][3];
            }
        }
    }

    #pragma unroll
    for (int n = 0; n < 4; ++n) {
        if (!valid[n]) continue;
        union { __half2 h2[2]; uint2 u; } pk;
        pk.h2[0] = __floats2half2_rn(acc[n][0], acc[n][1]);
        pk.h2[1] = __floats2half2_rn(acc[n][2], acc[n][3]);
        *(uint2*)(L + (size_t)(node0 + n) * 32 + r0) = pk.u;   // 8B aligned, normal store
    }
}

// ---------------------------------------------------------------------------
// Kernel 2: per-edge gather + sigmoid + clamp. 8 edges/thread.
// All streaming traffic (ei, et, out) is non-temporal so the 3.2 MB fp16
// table stays L2-resident; 16 independent gathers in flight per thread.
// ---------------------------------------------------------------------------
__global__ __launch_bounds__(256) void edge_score_kernel(
    const int* __restrict__ ei,      // (2, E) int32
    const int* __restrict__ et,      // (E,) int32
    const __half* __restrict__ L,    // (N, 32) fp16
    float* __restrict__ out,
    int num_edges)
{
    const int i = blockIdx.x * blockDim.x + threadIdx.x;   // octet index
    if (i * 8 >= num_edges) return;

    const i32x4* eis = (const i32x4*)ei;
    const i32x4* eid = (const i32x4*)(ei + num_edges);
    const i32x4* ett = (const i32x4*)et;

    const i32x4 sa = __builtin_nontemporal_load(&eis[2 * i]);
    const i32x4 sb = __builtin_nontemporal_load(&eis[2 * i + 1]);
    const i32x4 da = __builtin_nontemporal_load(&eid[2 * i]);
    const i32x4 db = __builtin_nontemporal_load(&eid[2 * i + 1]);
    const i32x4 ta = __builtin_nontemporal_load(&ett[2 * i]);
    const i32x4 tb = __builtin_nontemporal_load(&ett[2 * i + 1]);

    int s[8], d[8], t[8];
    #pragma unroll
    for (int j = 0; j < 4; ++j) {
        s[j] = sa[j]; s[4 + j] = sb[j];
        d[j] = da[j]; d[4 + j] = db[j];
        t[j] = ta[j]; t[4 + j] = tb[j];
    }

    // Issue all 16 gathers before any conversion/compute.
    __half hs[8], hd[8];
    #pragma unroll
    for (int j = 0; j < 8; ++j) hs[j] = L[(size_t)s[j] * 32 + t[j]];
    #pragma unroll
    for (int j = 0; j < 8; ++j) hd[j] = L[(size_t)d[j] * 32 + 16 + t[j]];

    f32x4 r[2];
    #pragma unroll
    for (int j = 0; j < 8; ++j) {
        const float sc = __half2float(hs[j]) + __half2float(hd[j]);
        const float att = 1.f / (1.f + __expf(-sc));
        r[j >> 2][j & 3] = fminf(fmaxf(att, 1e-5f), 0.99999f);
    }
    f32x4* o = (f32x4*)out;
    __builtin_nontemporal_store(r[0], &o[2 * i]);
    __builtin_nontemporal_store(r[1], &o[2 * i + 1]);
}

// Fallback: direct per-edge dot product in f32 (no workspace table).
__global__ void edge_direct_kernel(const float* __restrict__ x,
                                   const float* __restrict__ w,
                                   const int* __restrict__ ei,
                                   const int* __restrict__ et,
                                   float* __restrict__ out,
                                   int num_edges) {
    const int e = blockIdx.x * blockDim.x + threadIdx.x;
    if (e >= num_edges) return;
    const int s = ei[e];
    const int d = ei[num_edges + e];
    const int t = et[e];
    const float* xs = x + (size_t)s * INPUT_SIZE;
    const float* xd = x + (size_t)d * INPUT_SIZE;
    float acc = 0.f;
    #pragma unroll 4
    for (int k = 0; k < INPUT_SIZE; ++k)
        acc += xs[k] * w[k * NUM_REL + t] + xd[k] * w[(INPUT_SIZE + k) * NUM_REL + t];
    const float att = 1.f / (1.f + __expf(-acc));
    out[e] = fminf(fmaxf(att, 1e-5f), 0.99999f);
}

extern "C" void kernel_launch(void* const* d_in, const int* in_sizes, int n_in,
                              void* d_out, int out_size, void* d_ws, size_t ws_size,
                              hipStream_t stream) {
    const float* x  = (const float*)d_in[0];   // (50000, 128) f32
    const float* w  = (const float*)d_in[1];   // (256, 16) f32
    const int*   ei = (const int*)d_in[2];     // (2, E) int32
    const int*   et = (const int*)d_in[3];     // (E,) int32
    float* out = (float*)d_out;

    const int num_nodes = in_sizes[0] / INPUT_SIZE;
    const int num_edges = in_sizes[3];

    const size_t ws_needed = (size_t)num_nodes * 32 * sizeof(__half);

    if (ws_size >= ws_needed && (num_edges & 7) == 0) {
        __half* L = (__half*)d_ws;

        const int blocks1 = (num_nodes + 127) / 128;
        node_logits_kernel<<<blocks1, 256, 0, stream>>>(x, w, L, num_nodes);

        const int octs    = num_edges / 8;
        const int blocks2 = (octs + 255) / 256;
        edge_score_kernel<<<blocks2, 256, 0, stream>>>(ei, et, L, out, num_edges);
    } else {
        const int blocks = (num_edges + 255) / 256;
        edge_direct_kernel<<<blocks, 256, 0, stream>>>(x, w, ei, et, out, num_edges);
    }
}

// Round 4
// 43.582 us; speedup vs baseline: 1.3510x; 1.3510x over previous
//
#include <hip/hip_runtime.h>
#include <hip/hip_fp16.h>

#define INPUT_SIZE 128
#define NUM_REL 16

typedef int   i32x4 __attribute__((ext_vector_type(4)));
typedef float f32x4 __attribute__((ext_vector_type(4)));

// ---------------------------------------------------------------------------
// Kernel 1: per-node logit table, fp16 output.
//   L[n][r]    = x[n] . att_weight[0:128, r]      (r = 0..15, src half)
//   L[n][16+r] = x[n] . att_weight[128:256, r]    (dst half)
// Block: 256 threads = 64 nodes (782 blocks -> ~3 blocks/CU for latency
// hiding; R2's 128-node version ran at 1.5 blocks/CU). Tile: 2 nodes x 4 rels.
// w staged in LDS repacked to swc[k][32]; ds_read_b128 per 4 rels, 8 unique
// addrs/wave spanning all 32 banks once + broadcast -> conflict-free.
// ---------------------------------------------------------------------------
__global__ __launch_bounds__(256) void node_logits_kernel(
    const float* __restrict__ x,
    const float* __restrict__ w,     // (256,16) row-major
    __half* __restrict__ L,          // (num_nodes, 32) fp16
    int num_nodes)
{
    __shared__ float swc[128 * 32];  // swc[k*32 + r], 16 KB

    const int tid = threadIdx.x;

    // Stage + repack weights: swc[k][r] = r<16 ? w[k][r] : w[128+k][r-16]
    #pragma unroll
    for (int i = 0; i < 16; ++i) {
        const int idx = i * 256 + tid;        // 0..4095
        const int k = idx >> 5, r = idx & 31;
        swc[idx] = (r < 16) ? w[k * NUM_REL + r]
                            : w[(INPUT_SIZE + k) * NUM_REL + (r - 16)];
    }
    __syncthreads();

    const int ng = tid >> 3;                  // node group 0..31
    const int rg = tid & 7;                   // rel group  0..7
    const int node0 = blockIdx.x * 64 + ng * 2;
    const int r0 = rg * 4;

    const f32x4* xr[2];
    bool valid[2];
    #pragma unroll
    for (int n = 0; n < 2; ++n) {
        const int nn = node0 + n;
        valid[n] = (nn < num_nodes);
        const int cn = valid[n] ? nn : 0;     // clamp: safe read, store predicated
        xr[n] = (const f32x4*)(x + (size_t)cn * INPUT_SIZE);
    }

    float acc[2][4] = {};

    #pragma unroll 8
    for (int ks = 0; ks < 32; ++ks) {         // 4 k's per step
        f32x4 xv[2], wv[4];
        #pragma unroll
        for (int n = 0; n < 2; ++n) xv[n] = xr[n][ks];
        #pragma unroll
        for (int kk = 0; kk < 4; ++kk)
            wv[kk] = *(const f32x4*)&swc[(ks * 4 + kk) * 32 + r0];

        #pragma unroll
        for (int n = 0; n < 2; ++n) {
            #pragma unroll
            for (int c = 0; c < 4; ++c) {     // xv component c pairs with wv[c]
                acc[n][0] += xv[n][c] * wv[c][0];
                acc[n][1] += xv[n][c] * wv[c][1];
                acc[n][2] += xv[n][c] * wv[c][2];
                acc[n][3] += xv[n][c] * wv[c][3];
            }
        }
    }

    #pragma unroll
    for (int n = 0; n < 2; ++n) {
        if (!valid[n]) continue;
        union { __half2 h2[2]; uint2 u; } pk;
        pk.h2[0] = __floats2half2_rn(acc[n][0], acc[n][1]);
        pk.h2[1] = __floats2half2_rn(acc[n][2], acc[n][3]);
        *(uint2*)(L + (size_t)(node0 + n) * 32 + r0) = pk.u;   // 8B aligned
    }
}

// ---------------------------------------------------------------------------
// Kernel 2: per-edge gather + sigmoid + clamp. 8 edges/thread.
// Plain loads (R3 showed NT loads regress). NT only on the out STORE:
// no-allocate path removes 6.4 MB of L2 wash that evicts the gather table.
// 16 independent 2B gathers in flight per thread.
// ---------------------------------------------------------------------------
__global__ __launch_bounds__(256) void edge_score_kernel(
    const int* __restrict__ ei,      // (2, E) int32
    const int* __restrict__ et,      // (E,) int32
    const __half* __restrict__ L,    // (N, 32) fp16
    float* __restrict__ out,
    int num_edges)
{
    const int i = blockIdx.x * blockDim.x + threadIdx.x;   // octet index
    if (i * 8 >= num_edges) return;

    const i32x4* eis = (const i32x4*)ei;
    const i32x4* eid = (const i32x4*)(ei + num_edges);
    const i32x4* ett = (const i32x4*)et;

    const i32x4 sa = eis[2 * i],     sb = eis[2 * i + 1];
    const i32x4 da = eid[2 * i],     db = eid[2 * i + 1];
    const i32x4 ta = ett[2 * i],     tb = ett[2 * i + 1];

    int s[8], d[8], t[8];
    #pragma unroll
    for (int j = 0; j < 4; ++j) {
        s[j] = sa[j]; s[4 + j] = sb[j];
        d[j] = da[j]; d[4 + j] = db[j];
        t[j] = ta[j]; t[4 + j] = tb[j];
    }

    // Issue all 16 gathers before any conversion/compute.
    __half hs[8], hd[8];
    #pragma unroll
    for (int j = 0; j < 8; ++j) hs[j] = L[(size_t)s[j] * 32 + t[j]];
    #pragma unroll
    for (int j = 0; j < 8; ++j) hd[j] = L[(size_t)d[j] * 32 + 16 + t[j]];

    f32x4 r[2];
    #pragma unroll
    for (int j = 0; j < 8; ++j) {
        const float sc = __half2float(hs[j]) + __half2float(hd[j]);
        const float att = 1.f / (1.f + __expf(-sc));
        r[j >> 2][j & 3] = fminf(fmaxf(att, 1e-5f), 0.99999f);
    }
    f32x4* o = (f32x4*)out;
    __builtin_nontemporal_store(r[0], &o[2 * i]);
    __builtin_nontemporal_store(r[1], &o[2 * i + 1]);
}

// Fallback: direct per-edge dot product in f32 (no workspace table).
__global__ void edge_direct_kernel(const float* __restrict__ x,
                                   const float* __restrict__ w,
                                   const int* __restrict__ ei,
                                   const int* __restrict__ et,
                                   float* __restrict__ out,
                                   int num_edges) {
    const int e = blockIdx.x * blockDim.x + threadIdx.x;
    if (e >= num_edges) return;
    const int s = ei[e];
    const int d = ei[num_edges + e];
    const int t = et[e];
    const float* xs = x + (size_t)s * INPUT_SIZE;
    const float* xd = x + (size_t)d * INPUT_SIZE;
    float acc = 0.f;
    #pragma unroll 4
    for (int k = 0; k < INPUT_SIZE; ++k)
        acc += xs[k] * w[k * NUM_REL + t] + xd[k] * w[(INPUT_SIZE + k) * NUM_REL + t];
    const float att = 1.f / (1.f + __expf(-acc));
    out[e] = fminf(fmaxf(att, 1e-5f), 0.99999f);
}

extern "C" void kernel_launch(void* const* d_in, const int* in_sizes, int n_in,
                              void* d_out, int out_size, void* d_ws, size_t ws_size,
                              hipStream_t stream) {
    const float* x  = (const float*)d_in[0];   // (50000, 128) f32
    const float* w  = (const float*)d_in[1];   // (256, 16) f32
    const int*   ei = (const int*)d_in[2];     // (2, E) int32
    const int*   et = (const int*)d_in[3];     // (E,) int32
    float* out = (float*)d_out;

    const int num_nodes = in_sizes[0] / INPUT_SIZE;
    const int num_edges = in_sizes[3];

    const size_t ws_needed = (size_t)num_nodes * 32 * sizeof(__half);

    if (ws_size >= ws_needed && (num_edges & 7) == 0) {
        __half* L = (__half*)d_ws;

        const int blocks1 = (num_nodes + 63) / 64;
        node_logits_kernel<<<blocks1, 256, 0, stream>>>(x, w, L, num_nodes);

        const int octs    = num_edges / 8;
        const int blocks2 = (octs + 255) / 256;
        edge_score_kernel<<<blocks2, 256, 0, stream>>>(ei, et, L, out, num_edges);
    } else {
        const int blocks = (num_edges + 255) / 256;
        edge_direct_kernel<<<blocks, 256, 0, stream>>>(x, w, ei, et, out, num_edges);
    }
}